// Round 3
// baseline (391.694 us; speedup 1.0000x reference)
//
#include <hip/hip_runtime.h>

#define N_NODES 100000
#define N_EDGES 1600000
#define SCAN_BLOCKS 25          // 25 * 4096 = 102400 >= N_NODES

// ---------------------------------------------------------------------------
// CSR build (rebuilt every launch; ws is re-poisoned between calls).
// pos[e] = rank of edge e within its dst (atomic-return count), then scan,
// then an atomic-free scatter.
// ---------------------------------------------------------------------------
__global__ __launch_bounds__(1024) void k_zero(int* __restrict__ cnt) {
    int i = blockIdx.x * 1024 + threadIdx.x;
    if (i < N_NODES) cnt[i] = 0;
}

// Count + rank in one pass. High-occupancy latency-bound kernel: thousands
// of waves cover the ~700cy atomic round-trips (round-2 lesson: do NOT fuse
// this into the occupancy-starved matmul).
__global__ __launch_bounds__(256) void k_count_pos(const int* __restrict__ ei,
                                                   int* __restrict__ cnt,
                                                   int* __restrict__ pos) {
    const int e0 = (blockIdx.x * 256 + threadIdx.x) * 4;
    if (e0 >= N_EDGES) return;                 // N_EDGES % 4 == 0: all-or-none
    int4 d4 = *(const int4*)&ei[N_EDGES + e0];
    int4 p4;
    p4.x = atomicAdd(&cnt[d4.x], 1);
    p4.y = atomicAdd(&cnt[d4.y], 1);
    p4.z = atomicAdd(&cnt[d4.z], 1);
    p4.w = atomicAdd(&cnt[d4.w], 1);
    *(int4*)&pos[e0] = p4;
}

// Hierarchical scan, stage 1: each block scans a 4096-elem chunk (4/thread),
// writes chunk-local EXCLUSIVE scan to off[] and its chunk total to bsum[].
__global__ __launch_bounds__(1024) void k_scan_local(const int* __restrict__ cnt,
                                                     int* __restrict__ off,
                                                     int* __restrict__ bsum) {
    __shared__ int waveSums[16];
    const int tid  = threadIdx.x;
    const int lane = tid & 63;
    const int wid  = tid >> 6;
    const int base = blockIdx.x * 4096 + tid * 4;
    int v0 = 0, v1 = 0, v2 = 0, v3 = 0;
    const bool inR = (base < N_NODES);          // N_NODES % 4 == 0: all-or-none
    if (inR) { int4 q = *(const int4*)&cnt[base]; v0 = q.x; v1 = q.y; v2 = q.z; v3 = q.w; }
    int s = v0 + v1 + v2 + v3;
    int incl = s;
    #pragma unroll
    for (int d = 1; d < 64; d <<= 1) {
        int n = __shfl_up(incl, d, 64);
        if (lane >= d) incl += n;
    }
    if (lane == 63) waveSums[wid] = incl;
    __syncthreads();
    int waveOff = 0, total = 0;
    #pragma unroll
    for (int w = 0; w < 16; ++w) {
        int ws = waveSums[w];
        waveOff += (w < wid) ? ws : 0;
        total   += ws;
    }
    if (inR) {
        int e0 = waveOff + incl - s;            // chunk-local exclusive
        int4 o = {e0, e0 + v0, e0 + v0 + v1, e0 + v0 + v1 + v2};
        *(int4*)&off[base] = o;
    }
    if (tid == 0) bsum[blockIdx.x] = total;
}

// Stage 2: add chunk base (redundant mini-scan of bsum per block), finalize
// off[]. off[N_NODES] is the known total.
__global__ __launch_bounds__(1024) void k_scan_fix(int* __restrict__ off,
                                                   const int* __restrict__ bsum) {
    const int b = blockIdx.x;
    int add = 0;
    for (int j = 0; j < b; ++j) add += bsum[j];
    const int base = b * 4096 + threadIdx.x * 4;
    if (base < N_NODES) {
        int4 q = *(int4*)&off[base];
        q.x += add; q.y += add; q.z += add; q.w += add;
        *(int4*)&off[base] = q;
    }
    if (b == 0 && threadIdx.x == 0) off[N_NODES] = N_EDGES;
}

// Atomic-free scatter: srcS[off[dst[e]] + pos[e]] = src[e].
// Coalesced dst/src/pos streams, off gather hits the 400 KB L2-resident
// table, scattered 4B payload writes (no atomics, 1x reads).
__global__ __launch_bounds__(256) void k_scatter(const int* __restrict__ ei,
                                                 const int* __restrict__ pos,
                                                 const int* __restrict__ off,
                                                 int* __restrict__ srcS) {
    const int e0 = (blockIdx.x * 256 + threadIdx.x) * 4;
    if (e0 >= N_EDGES) return;                 // N_EDGES % 4 == 0: all-or-none
    int4 d4 = *(const int4*)&ei[N_EDGES + e0];
    int4 s4 = *(const int4*)&ei[e0];
    int4 p4 = *(const int4*)&pos[e0];
    srcS[off[d4.x] + p4.x] = s4.x;
    srcS[off[d4.y] + p4.y] = s4.y;
    srcS[off[d4.z] + p4.z] = s4.z;
    srcS[off[d4.w] + p4.w] = s4.w;
}

// ---------------------------------------------------------------------------
// Gather-aggregate: z[n] = y[n] + sum_{e: dst==n} y[src_e].  One wave per
// node, lane == channel (64 ch). One coalesced srcS load per 64 edges,
// __shfl broadcast of indices, 16 independent row-gathers in flight
// (mean degree = 16, so the typical node is one burst).
// ---------------------------------------------------------------------------
__global__ __launch_bounds__(256) void k_gather_agg(const int* __restrict__ off,
                                                    const int* __restrict__ srcS,
                                                    const float* __restrict__ y,
                                                    float* __restrict__ z) {
    const int node = blockIdx.x * 4 + (threadIdx.x >> 6);
    if (node >= N_NODES) return;
    const int lane = threadIdx.x & 63;
    const int beg = off[node];
    const int end = off[node + 1];
    float acc = y[((size_t)node << 6) + lane];
    int i = beg;
    while (i < end) {
        const int rem  = end - i;
        const int take = rem < 64 ? rem : 64;
        int idx = i + lane;
        if (idx > end - 1) idx = end - 1;       // in-range duplicate for lanes >= take
        const int sv = srcS[idx];               // coalesced: 64 edge indices / wave
        int j = 0;
        for (; j + 16 <= take; j += 16) {
            const int s0 = __shfl(sv, j + 0),  s1 = __shfl(sv, j + 1);
            const int s2 = __shfl(sv, j + 2),  s3 = __shfl(sv, j + 3);
            const int s4 = __shfl(sv, j + 4),  s5 = __shfl(sv, j + 5);
            const int s6 = __shfl(sv, j + 6),  s7 = __shfl(sv, j + 7);
            const int s8 = __shfl(sv, j + 8),  s9 = __shfl(sv, j + 9);
            const int sA = __shfl(sv, j + 10), sB = __shfl(sv, j + 11);
            const int sC = __shfl(sv, j + 12), sD = __shfl(sv, j + 13);
            const int sE = __shfl(sv, j + 14), sF = __shfl(sv, j + 15);
            const float v0 = y[((size_t)s0 << 6) + lane];
            const float v1 = y[((size_t)s1 << 6) + lane];
            const float v2 = y[((size_t)s2 << 6) + lane];
            const float v3 = y[((size_t)s3 << 6) + lane];
            const float v4 = y[((size_t)s4 << 6) + lane];
            const float v5 = y[((size_t)s5 << 6) + lane];
            const float v6 = y[((size_t)s6 << 6) + lane];
            const float v7 = y[((size_t)s7 << 6) + lane];
            const float v8 = y[((size_t)s8 << 6) + lane];
            const float v9 = y[((size_t)s9 << 6) + lane];
            const float vA = y[((size_t)sA << 6) + lane];
            const float vB = y[((size_t)sB << 6) + lane];
            const float vC = y[((size_t)sC << 6) + lane];
            const float vD = y[((size_t)sD << 6) + lane];
            const float vE = y[((size_t)sE << 6) + lane];
            const float vF = y[((size_t)sF << 6) + lane];
            acc += (((v0 + v1) + (v2 + v3)) + ((v4 + v5) + (v6 + v7)))
                 + (((v8 + v9) + (vA + vB)) + ((vC + vD) + (vE + vF)));
        }
        for (; j + 4 <= take; j += 4) {
            const int s0 = __shfl(sv, j + 0), s1 = __shfl(sv, j + 1);
            const int s2 = __shfl(sv, j + 2), s3 = __shfl(sv, j + 3);
            const float v0 = y[((size_t)s0 << 6) + lane];
            const float v1 = y[((size_t)s1 << 6) + lane];
            const float v2 = y[((size_t)s2 << 6) + lane];
            const float v3 = y[((size_t)s3 << 6) + lane];
            acc += (v0 + v1) + (v2 + v3);
        }
        for (; j < take; ++j) {
            const int s = __shfl(sv, j);
            acc += y[((size_t)s << 6) + lane];
        }
        i += take;
    }
    z[((size_t)node << 6) + lane] = acc;
}

// ---------------------------------------------------------------------------
// K1: y = x @ W1  (N x 128 @ 128 x 64).  64x64 block tile, 4x4 register tile
// per thread, X staged TRANSPOSED in LDS (stride 68 keeps 16B alignment).
// ---------------------------------------------------------------------------
#define FMA16()                                                       \
    do {                                                              \
        acc0.x += a.x * w.x; acc0.y += a.x * w.y;                     \
        acc0.z += a.x * w.z; acc0.w += a.x * w.w;                     \
        acc1.x += a.y * w.x; acc1.y += a.y * w.y;                     \
        acc1.z += a.y * w.z; acc1.w += a.y * w.w;                     \
        acc2.x += a.z * w.x; acc2.y += a.z * w.y;                     \
        acc2.z += a.z * w.z; acc2.w += a.z * w.w;                     \
        acc3.x += a.w * w.x; acc3.y += a.w * w.y;                     \
        acc3.z += a.w * w.z; acc3.w += a.w * w.w;                     \
    } while (0)

__global__ __launch_bounds__(256) void k_mm1(const float* __restrict__ x,
                                             const float* __restrict__ W1,
                                             float* __restrict__ y) {
    __shared__ float sW[128 * 64];    // 32 KB, [k][n]
    __shared__ float sxT[128 * 68];   // 34 KB, [k][m] transposed, stride 68
    const int tid  = threadIdx.x;
    const int row0 = blockIdx.x * 64;
    #pragma unroll
    for (int i = tid * 4; i < 128 * 64; i += 1024)
        *(float4*)&sW[i] = *(const float4*)&W1[i];
    #pragma unroll 8
    for (int i = tid; i < 64 * 128; i += 256) {
        int m = i >> 7, k = i & 127;                 // coalesced in k
        int r = row0 + m; if (r >= N_NODES) r = N_NODES - 1;
        sxT[k * 68 + m] = x[(size_t)r * 128 + k];
    }
    __syncthreads();
    const int tx = tid & 15;          // cols tx*4 .. +3
    const int ty = tid >> 4;          // rows ty*4 .. +3
    float4 acc0 = {0.f,0.f,0.f,0.f}, acc1 = {0.f,0.f,0.f,0.f};
    float4 acc2 = {0.f,0.f,0.f,0.f}, acc3 = {0.f,0.f,0.f,0.f};
    #pragma unroll 4
    for (int k = 0; k < 128; ++k) {
        float4 a = *(const float4*)&sxT[k * 68 + ty * 4];
        float4 w = *(const float4*)&sW[k * 64 + tx * 4];
        FMA16();
    }
    const int rb = row0 + ty * 4;
    if (rb + 0 < N_NODES) *(float4*)&y[(size_t)(rb + 0) * 64 + tx * 4] = acc0;
    if (rb + 1 < N_NODES) *(float4*)&y[(size_t)(rb + 1) * 64 + tx * 4] = acc1;
    if (rb + 2 < N_NODES) *(float4*)&y[(size_t)(rb + 2) * 64 + tx * 4] = acc2;
    if (rb + 3 < N_NODES) *(float4*)&y[(size_t)(rb + 3) * 64 + tx * 4] = acc3;
}

// ---------------------------------------------------------------------------
// K3: h1 = relu(z1 + b1);  y2 = h1 @ W2  (64x64).  Same register-tiled scheme.
// ---------------------------------------------------------------------------
__global__ __launch_bounds__(256) void k_relu_mm2(const float* __restrict__ z1,
                                                  const float* __restrict__ b1,
                                                  const float* __restrict__ W2,
                                                  float* __restrict__ y2) {
    __shared__ float sW[64 * 64];     // 16 KB, [k][n]
    __shared__ float shT[64 * 68];    // 17 KB, [k][m] transposed
    const int tid  = threadIdx.x;
    const int row0 = blockIdx.x * 64;
    #pragma unroll
    for (int i = tid * 4; i < 64 * 64; i += 1024)
        *(float4*)&sW[i] = *(const float4*)&W2[i];
    #pragma unroll 8
    for (int i = tid; i < 64 * 64; i += 256) {
        int m = i >> 6, k = i & 63;                  // coalesced in k
        int r = row0 + m; if (r >= N_NODES) r = N_NODES - 1;
        shT[k * 68 + m] = fmaxf(z1[(size_t)r * 64 + k] + b1[k], 0.f);
    }
    __syncthreads();
    const int tx = tid & 15;
    const int ty = tid >> 4;
    float4 acc0 = {0.f,0.f,0.f,0.f}, acc1 = {0.f,0.f,0.f,0.f};
    float4 acc2 = {0.f,0.f,0.f,0.f}, acc3 = {0.f,0.f,0.f,0.f};
    #pragma unroll 4
    for (int k = 0; k < 64; ++k) {
        float4 a = *(const float4*)&shT[k * 68 + ty * 4];
        float4 w = *(const float4*)&sW[k * 64 + tx * 4];
        FMA16();
    }
    const int rb = row0 + ty * 4;
    if (rb + 0 < N_NODES) *(float4*)&y2[(size_t)(rb + 0) * 64 + tx * 4] = acc0;
    if (rb + 1 < N_NODES) *(float4*)&y2[(size_t)(rb + 1) * 64 + tx * 4] = acc1;
    if (rb + 2 < N_NODES) *(float4*)&y2[(size_t)(rb + 2) * 64 + tx * 4] = acc2;
    if (rb + 3 < N_NODES) *(float4*)&y2[(size_t)(rb + 3) * 64 + tx * 4] = acc3;
}

// ---------------------------------------------------------------------------
// K5: per-node tail: h2 = relu(z2+b2); h3 = relu(h2@W3+b3); out = h3@W4+b4.
// ---------------------------------------------------------------------------
__global__ __launch_bounds__(256) void k_tail(const float* __restrict__ z2,
                                              const float* __restrict__ b2,
                                              const float* __restrict__ W3,
                                              const float* __restrict__ b3,
                                              const float* __restrict__ W4,
                                              const float* __restrict__ b4,
                                              float* __restrict__ out) {
    __shared__ float sW3[64 * 16];
    __shared__ float sW4[16];
    __shared__ float sb3[16];
    const int tid = threadIdx.x;
    *(float4*)&sW3[tid * 4] = *(const float4*)&W3[tid * 4];
    if (tid < 16) { sW4[tid] = W4[tid]; sb3[tid] = b3[tid]; }
    __syncthreads();
    const int node = blockIdx.x * 256 + tid;
    if (node >= N_NODES) return;

    float h[64];
    const float4* zp = (const float4*)&z2[(size_t)node * 64];
    #pragma unroll
    for (int i = 0; i < 16; ++i) {
        float4 v  = zp[i];
        float4 bb = *(const float4*)&b2[i * 4];
        h[i * 4 + 0] = fmaxf(v.x + bb.x, 0.f);
        h[i * 4 + 1] = fmaxf(v.y + bb.y, 0.f);
        h[i * 4 + 2] = fmaxf(v.z + bb.z, 0.f);
        h[i * 4 + 3] = fmaxf(v.w + bb.w, 0.f);
    }
    float acc[16];
    #pragma unroll
    for (int j = 0; j < 16; ++j) acc[j] = sb3[j];
    #pragma unroll 8
    for (int k = 0; k < 64; ++k) {
        float hv = h[k];
        #pragma unroll
        for (int j = 0; j < 16; ++j) acc[j] += hv * sW3[k * 16 + j];
    }
    float o = b4[0];
    #pragma unroll
    for (int j = 0; j < 16; ++j) o += fmaxf(acc[j], 0.f) * sW4[j];
    out[node] = o;
}

extern "C" void kernel_launch(void* const* d_in, const int* in_sizes, int n_in,
                              void* d_out, int out_size, void* d_ws, size_t ws_size,
                              hipStream_t stream) {
    const float* x  = (const float*)d_in[0];
    const int*   ei = (const int*)d_in[1];
    const float* W1 = (const float*)d_in[2];
    const float* b1 = (const float*)d_in[3];
    const float* W2 = (const float*)d_in[4];
    const float* b2 = (const float*)d_in[5];
    const float* W3 = (const float*)d_in[6];
    const float* b3 = (const float*)d_in[7];
    const float* W4 = (const float*)d_in[8];
    const float* b4 = (const float*)d_in[9];
    float* out = (float*)d_out;

    // ws layout: bufA | bufB | cnt | off | srcSorted | bsum
    // pos[] aliases bufB: written by k_count_pos, consumed by k_scatter,
    // both strictly before the first k_gather_agg overwrites bufB with z1.
    float* bufA = (float*)d_ws;
    float* bufB = bufA + (size_t)N_NODES * 64;
    int*   cnt  = (int*)(bufB + (size_t)N_NODES * 64);
    int*   off  = cnt + N_NODES;
    int*   srcS = off + N_NODES + 4;          // keep 16B alignment slack
    int*   bsum = srcS + N_EDGES;
    int*   pos  = (int*)bufB;

    const int mmBlocks   = (N_NODES + 63) / 64;       // 1563
    const int edgeBlocks = (N_EDGES / 4 + 255) / 256; // 1563 (4 edges/thread)
    const int aggBlocks  = (N_NODES + 3) / 4;         // 25000
    const int tailBlocks = (N_NODES + 255) / 256;     // 391

    // CSR build
    k_zero<<<(N_NODES + 1023) / 1024, 1024, 0, stream>>>(cnt);
    k_count_pos<<<edgeBlocks, 256, 0, stream>>>(ei, cnt, pos);
    k_scan_local<<<SCAN_BLOCKS, 1024, 0, stream>>>(cnt, off, bsum);
    k_scan_fix<<<SCAN_BLOCKS, 1024, 0, stream>>>(off, bsum);
    k_scatter<<<edgeBlocks, 256, 0, stream>>>(ei, pos, off, srcS);

    // conv1: y1 = x@W1 ; z1 = y1 + gather-sum(y1)   (gather overwrites pos)
    k_mm1<<<mmBlocks, 256, 0, stream>>>(x, W1, bufA);
    k_gather_agg<<<aggBlocks, 256, 0, stream>>>(off, srcS, bufA, bufB);
    // conv2: y2 = relu(z1+b1)@W2 ; z2 = y2 + gather-sum(y2)
    k_relu_mm2<<<mmBlocks, 256, 0, stream>>>(bufB, b1, W2, bufA);
    k_gather_agg<<<aggBlocks, 256, 0, stream>>>(off, srcS, bufA, bufB);
    // head
    k_tail<<<tailBlocks, 256, 0, stream>>>(bufB, b2, W3, b3, W4, b4, out);
}

// Round 4
// 321.368 us; speedup vs baseline: 1.2188x; 1.2188x over previous
//
#include <hip/hip_runtime.h>

#define N_NODES 100000
#define N_EDGES 1600000
#define NBUCK 196            // ceil(N_NODES / 512); bucket = dst >> 9
#define BUCAP 10240          // per-bucket capacity (mean 8192, sigma ~90: +22 sigma)
#define P1_EDGES 8192        // edges per P1 block
#define NP1 196              // ceil(N_EDGES / P1_EDGES) = 195.3 -> 196

// ---------------------------------------------------------------------------
// CSR build, atomic-light bucket sort (rebuilt every launch; ws re-poisoned).
// P1: partition edges into 196 coarse buckets (512 nodes each) using LDS
//     histograms; ONE global atomic per (block,bucket) pair (38K total).
// P2: per bucket, build node-level CSR entirely in LDS; coalesced output.
// Round-3 lesson: 1.6M global atomic-returns on a 400KB table = 68us of
// per-line serialization (VALUBusy 0.3%). Keep contended atomics in LDS.
// ---------------------------------------------------------------------------
__global__ __launch_bounds__(256) void k_zero_cur(int* __restrict__ cursor) {
    if (threadIdx.x < NBUCK) cursor[threadIdx.x] = 0;
}

__global__ __launch_bounds__(1024) void k_p1(const int* __restrict__ ei,
                                             int* __restrict__ cursor,
                                             int* __restrict__ bArr) {
    __shared__ int hist[NBUCK];
    const int tid = threadIdx.x;
    if (tid < NBUCK) hist[tid] = 0;

    const int eb = blockIdx.x * P1_EDGES;
    int d[8], s[8];
    #pragma unroll
    for (int j = 0; j < 2; ++j) {
        const int e = eb + j * 4096 + tid * 4;
        if (e < N_EDGES) {                       // N_EDGES % 4 == 0: all-or-none
            int4 dd = *(const int4*)&ei[N_EDGES + e];
            int4 ss = *(const int4*)&ei[e];
            d[j*4+0] = dd.x; d[j*4+1] = dd.y; d[j*4+2] = dd.z; d[j*4+3] = dd.w;
            s[j*4+0] = ss.x; s[j*4+1] = ss.y; s[j*4+2] = ss.z; s[j*4+3] = ss.w;
        } else {
            d[j*4+0] = -1; d[j*4+1] = -1; d[j*4+2] = -1; d[j*4+3] = -1;
            s[j*4+0] = 0;  s[j*4+1] = 0;  s[j*4+2] = 0;  s[j*4+3] = 0;
        }
    }
    __syncthreads();
    #pragma unroll
    for (int j = 0; j < 8; ++j)
        if (d[j] >= 0) atomicAdd(&hist[d[j] >> 9], 1);
    __syncthreads();
    if (tid < NBUCK) {
        int c = hist[tid];
        int base = atomicAdd(&cursor[tid], c);   // the ONLY contended global atomic
        hist[tid] = base;                        // reuse hist as write cursor
    }
    __syncthreads();
    #pragma unroll
    for (int j = 0; j < 8; ++j)
        if (d[j] >= 0) {
            int bk  = d[j] >> 9;
            int pos = atomicAdd(&hist[bk], 1);   // LDS rank -> base+rank
            if (pos < BUCAP)
                bArr[bk * BUCAP + pos] = ((d[j] & 511) << 17) | s[j];
        }
}

__global__ __launch_bounds__(1024) void k_p2(const int* __restrict__ bArr,
                                             const int* __restrict__ cursor,
                                             int* __restrict__ srcS,
                                             int* __restrict__ off) {
    __shared__ int hist[512];
    __shared__ int wtot[8];
    __shared__ int curL[NBUCK];
    __shared__ int ordered[BUCAP];
    const int tid = threadIdx.x;
    const int b   = blockIdx.x;
    if (tid < 512)   hist[tid] = 0;
    if (tid < NBUCK) curL[tid] = cursor[tid];
    __syncthreads();

    int n = curL[b]; if (n > BUCAP) n = BUCAP;
    int gBase = 0;
    for (int j = 0; j < NBUCK; ++j) gBase += (j < b) ? curL[j] : 0;   // LDS broadcast

    int pk[10];                                  // static-indexed (rule #20)
    #pragma unroll
    for (int j = 0; j < 10; ++j) {
        int i = tid + j * 1024;
        pk[j] = (i < n) ? bArr[b * BUCAP + i] : -1;
    }
    #pragma unroll
    for (int j = 0; j < 10; ++j)
        if (pk[j] >= 0) atomicAdd(&hist[pk[j] >> 17], 1);
    __syncthreads();

    // exclusive scan of hist[512]: 8 waves shfl-scan + cross-wave fixup
    int v = 0, incl = 0;
    if (tid < 512) {
        v = hist[tid]; incl = v;
        #pragma unroll
        for (int dd = 1; dd < 64; dd <<= 1) {
            int t = __shfl_up(incl, dd, 64);
            if ((tid & 63) >= dd) incl += t;
        }
        if ((tid & 63) == 63) wtot[tid >> 6] = incl;
    }
    __syncthreads();
    if (tid < 512) {
        int add = 0;
        #pragma unroll
        for (int w = 0; w < 8; ++w) add += (w < (tid >> 6)) ? wtot[w] : 0;
        int ex = add + incl - v;
        hist[tid] = ex;                          // becomes rank cursor for phase B
        int node = b * 512 + tid;
        if (node < N_NODES) off[node] = gBase + ex;
    }
    if (b == NBUCK - 1 && tid == 0) off[N_NODES] = N_EDGES;
    __syncthreads();

    #pragma unroll
    for (int j = 0; j < 10; ++j)
        if (pk[j] >= 0) {
            int dl  = pk[j] >> 17;
            int pos = atomicAdd(&hist[dl], 1);
            ordered[pos] = pk[j] & 0x1FFFF;
        }
    __syncthreads();
    for (int i = tid; i < n; i += 1024) srcS[gBase + i] = ordered[i];
}

// ---------------------------------------------------------------------------
// Gather-aggregate: z[n] = y[n] + sum_{e: dst==n} y[src_e].  One wave per
// node, lane == channel (64 ch). One coalesced srcS load per 64 edges,
// __shfl broadcast of indices, 16 independent row-gathers in flight.
// ---------------------------------------------------------------------------
__global__ __launch_bounds__(256) void k_gather_agg(const int* __restrict__ off,
                                                    const int* __restrict__ srcS,
                                                    const float* __restrict__ y,
                                                    float* __restrict__ z) {
    const int node = blockIdx.x * 4 + (threadIdx.x >> 6);
    if (node >= N_NODES) return;
    const int lane = threadIdx.x & 63;
    const int beg = off[node];
    const int end = off[node + 1];
    float acc = y[((size_t)node << 6) + lane];
    int i = beg;
    while (i < end) {
        const int rem  = end - i;
        const int take = rem < 64 ? rem : 64;
        int idx = i + lane;
        if (idx > end - 1) idx = end - 1;       // in-range duplicate for lanes >= take
        const int sv = srcS[idx];               // coalesced: 64 edge indices / wave
        int j = 0;
        for (; j + 16 <= take; j += 16) {
            const int s0 = __shfl(sv, j + 0),  s1 = __shfl(sv, j + 1);
            const int s2 = __shfl(sv, j + 2),  s3 = __shfl(sv, j + 3);
            const int s4 = __shfl(sv, j + 4),  s5 = __shfl(sv, j + 5);
            const int s6 = __shfl(sv, j + 6),  s7 = __shfl(sv, j + 7);
            const int s8 = __shfl(sv, j + 8),  s9 = __shfl(sv, j + 9);
            const int sA = __shfl(sv, j + 10), sB = __shfl(sv, j + 11);
            const int sC = __shfl(sv, j + 12), sD = __shfl(sv, j + 13);
            const int sE = __shfl(sv, j + 14), sF = __shfl(sv, j + 15);
            const float v0 = y[((size_t)s0 << 6) + lane];
            const float v1 = y[((size_t)s1 << 6) + lane];
            const float v2 = y[((size_t)s2 << 6) + lane];
            const float v3 = y[((size_t)s3 << 6) + lane];
            const float v4 = y[((size_t)s4 << 6) + lane];
            const float v5 = y[((size_t)s5 << 6) + lane];
            const float v6 = y[((size_t)s6 << 6) + lane];
            const float v7 = y[((size_t)s7 << 6) + lane];
            const float v8 = y[((size_t)s8 << 6) + lane];
            const float v9 = y[((size_t)s9 << 6) + lane];
            const float vA = y[((size_t)sA << 6) + lane];
            const float vB = y[((size_t)sB << 6) + lane];
            const float vC = y[((size_t)sC << 6) + lane];
            const float vD = y[((size_t)sD << 6) + lane];
            const float vE = y[((size_t)sE << 6) + lane];
            const float vF = y[((size_t)sF << 6) + lane];
            acc += (((v0 + v1) + (v2 + v3)) + ((v4 + v5) + (v6 + v7)))
                 + (((v8 + v9) + (vA + vB)) + ((vC + vD) + (vE + vF)));
        }
        for (; j + 4 <= take; j += 4) {
            const int s0 = __shfl(sv, j + 0), s1 = __shfl(sv, j + 1);
            const int s2 = __shfl(sv, j + 2), s3 = __shfl(sv, j + 3);
            const float v0 = y[((size_t)s0 << 6) + lane];
            const float v1 = y[((size_t)s1 << 6) + lane];
            const float v2 = y[((size_t)s2 << 6) + lane];
            const float v3 = y[((size_t)s3 << 6) + lane];
            acc += (v0 + v1) + (v2 + v3);
        }
        for (; j < take; ++j) {
            const int s = __shfl(sv, j);
            acc += y[((size_t)s << 6) + lane];
        }
        i += take;
    }
    z[((size_t)node << 6) + lane] = acc;
}

// ---------------------------------------------------------------------------
// K1: y = x @ W1  (N x 128 @ 128 x 64).  64x64 block tile, 4x4 register tile
// per thread, X staged TRANSPOSED in LDS (stride 68 keeps 16B alignment).
// ---------------------------------------------------------------------------
#define FMA16()                                                       \
    do {                                                              \
        acc0.x += a.x * w.x; acc0.y += a.x * w.y;                     \
        acc0.z += a.x * w.z; acc0.w += a.x * w.w;                     \
        acc1.x += a.y * w.x; acc1.y += a.y * w.y;                     \
        acc1.z += a.y * w.z; acc1.w += a.y * w.w;                     \
        acc2.x += a.z * w.x; acc2.y += a.z * w.y;                     \
        acc2.z += a.z * w.z; acc2.w += a.z * w.w;                     \
        acc3.x += a.w * w.x; acc3.y += a.w * w.y;                     \
        acc3.z += a.w * w.z; acc3.w += a.w * w.w;                     \
    } while (0)

__global__ __launch_bounds__(256) void k_mm1(const float* __restrict__ x,
                                             const float* __restrict__ W1,
                                             float* __restrict__ y) {
    __shared__ float sW[128 * 64];    // 32 KB, [k][n]
    __shared__ float sxT[128 * 68];   // 34 KB, [k][m] transposed, stride 68
    const int tid  = threadIdx.x;
    const int row0 = blockIdx.x * 64;
    #pragma unroll
    for (int i = tid * 4; i < 128 * 64; i += 1024)
        *(float4*)&sW[i] = *(const float4*)&W1[i];
    #pragma unroll 8
    for (int i = tid; i < 64 * 128; i += 256) {
        int m = i >> 7, k = i & 127;                 // coalesced in k
        int r = row0 + m; if (r >= N_NODES) r = N_NODES - 1;
        sxT[k * 68 + m] = x[(size_t)r * 128 + k];
    }
    __syncthreads();
    const int tx = tid & 15;          // cols tx*4 .. +3
    const int ty = tid >> 4;          // rows ty*4 .. +3
    float4 acc0 = {0.f,0.f,0.f,0.f}, acc1 = {0.f,0.f,0.f,0.f};
    float4 acc2 = {0.f,0.f,0.f,0.f}, acc3 = {0.f,0.f,0.f,0.f};
    #pragma unroll 4
    for (int k = 0; k < 128; ++k) {
        float4 a = *(const float4*)&sxT[k * 68 + ty * 4];
        float4 w = *(const float4*)&sW[k * 64 + tx * 4];
        FMA16();
    }
    const int rb = row0 + ty * 4;
    if (rb + 0 < N_NODES) *(float4*)&y[(size_t)(rb + 0) * 64 + tx * 4] = acc0;
    if (rb + 1 < N_NODES) *(float4*)&y[(size_t)(rb + 1) * 64 + tx * 4] = acc1;
    if (rb + 2 < N_NODES) *(float4*)&y[(size_t)(rb + 2) * 64 + tx * 4] = acc2;
    if (rb + 3 < N_NODES) *(float4*)&y[(size_t)(rb + 3) * 64 + tx * 4] = acc3;
}

// ---------------------------------------------------------------------------
// K3: h1 = relu(z1 + b1);  y2 = h1 @ W2  (64x64).  Same register-tiled scheme.
// ---------------------------------------------------------------------------
__global__ __launch_bounds__(256) void k_relu_mm2(const float* __restrict__ z1,
                                                  const float* __restrict__ b1,
                                                  const float* __restrict__ W2,
                                                  float* __restrict__ y2) {
    __shared__ float sW[64 * 64];     // 16 KB, [k][n]
    __shared__ float shT[64 * 68];    // 17 KB, [k][m] transposed
    const int tid  = threadIdx.x;
    const int row0 = blockIdx.x * 64;
    #pragma unroll
    for (int i = tid * 4; i < 64 * 64; i += 1024)
        *(float4*)&sW[i] = *(const float4*)&W2[i];
    #pragma unroll 8
    for (int i = tid; i < 64 * 64; i += 256) {
        int m = i >> 6, k = i & 63;                  // coalesced in k
        int r = row0 + m; if (r >= N_NODES) r = N_NODES - 1;
        shT[k * 68 + m] = fmaxf(z1[(size_t)r * 64 + k] + b1[k], 0.f);
    }
    __syncthreads();
    const int tx = tid & 15;
    const int ty = tid >> 4;
    float4 acc0 = {0.f,0.f,0.f,0.f}, acc1 = {0.f,0.f,0.f,0.f};
    float4 acc2 = {0.f,0.f,0.f,0.f}, acc3 = {0.f,0.f,0.f,0.f};
    #pragma unroll 4
    for (int k = 0; k < 64; ++k) {
        float4 a = *(const float4*)&shT[k * 68 + ty * 4];
        float4 w = *(const float4*)&sW[k * 64 + tx * 4];
        FMA16();
    }
    const int rb = row0 + ty * 4;
    if (rb + 0 < N_NODES) *(float4*)&y2[(size_t)(rb + 0) * 64 + tx * 4] = acc0;
    if (rb + 1 < N_NODES) *(float4*)&y2[(size_t)(rb + 1) * 64 + tx * 4] = acc1;
    if (rb + 2 < N_NODES) *(float4*)&y2[(size_t)(rb + 2) * 64 + tx * 4] = acc2;
    if (rb + 3 < N_NODES) *(float4*)&y2[(size_t)(rb + 3) * 64 + tx * 4] = acc3;
}

// ---------------------------------------------------------------------------
// K5: per-node tail: h2 = relu(z2+b2); h3 = relu(h2@W3+b3); out = h3@W4+b4.
// ---------------------------------------------------------------------------
__global__ __launch_bounds__(256) void k_tail(const float* __restrict__ z2,
                                              const float* __restrict__ b2,
                                              const float* __restrict__ W3,
                                              const float* __restrict__ b3,
                                              const float* __restrict__ W4,
                                              const float* __restrict__ b4,
                                              float* __restrict__ out) {
    __shared__ float sW3[64 * 16];
    __shared__ float sW4[16];
    __shared__ float sb3[16];
    const int tid = threadIdx.x;
    *(float4*)&sW3[tid * 4] = *(const float4*)&W3[tid * 4];
    if (tid < 16) { sW4[tid] = W4[tid]; sb3[tid] = b3[tid]; }
    __syncthreads();
    const int node = blockIdx.x * 256 + tid;
    if (node >= N_NODES) return;

    float h[64];
    const float4* zp = (const float4*)&z2[(size_t)node * 64];
    #pragma unroll
    for (int i = 0; i < 16; ++i) {
        float4 v  = zp[i];
        float4 bb = *(const float4*)&b2[i * 4];
        h[i * 4 + 0] = fmaxf(v.x + bb.x, 0.f);
        h[i * 4 + 1] = fmaxf(v.y + bb.y, 0.f);
        h[i * 4 + 2] = fmaxf(v.z + bb.z, 0.f);
        h[i * 4 + 3] = fmaxf(v.w + bb.w, 0.f);
    }
    float acc[16];
    #pragma unroll
    for (int j = 0; j < 16; ++j) acc[j] = sb3[j];
    #pragma unroll 8
    for (int k = 0; k < 64; ++k) {
        float hv = h[k];
        #pragma unroll
        for (int j = 0; j < 16; ++j) acc[j] += hv * sW3[k * 16 + j];
    }
    float o = b4[0];
    #pragma unroll
    for (int j = 0; j < 16; ++j) o += fmaxf(acc[j], 0.f) * sW4[j];
    out[node] = o;
}

extern "C" void kernel_launch(void* const* d_in, const int* in_sizes, int n_in,
                              void* d_out, int out_size, void* d_ws, size_t ws_size,
                              hipStream_t stream) {
    const float* x  = (const float*)d_in[0];
    const int*   ei = (const int*)d_in[1];
    const float* W1 = (const float*)d_in[2];
    const float* b1 = (const float*)d_in[3];
    const float* W2 = (const float*)d_in[4];
    const float* b2 = (const float*)d_in[5];
    const float* W3 = (const float*)d_in[6];
    const float* b3 = (const float*)d_in[7];
    const float* W4 = (const float*)d_in[8];
    const float* b4 = (const float*)d_in[9];
    float* out = (float*)d_out;

    // ws layout: bufA | bufB | off | srcS | cursor
    // bucketArr (196*10240*4B = 8.03MB) aliases bufB: written by k_p1, read
    // by k_p2, both strictly before gather1 overwrites bufB with z1.
    float* bufA   = (float*)d_ws;
    float* bufB   = bufA + (size_t)N_NODES * 64;
    int*   off    = (int*)(bufB + (size_t)N_NODES * 64);
    int*   srcS   = off + N_NODES + 4;        // 16B alignment slack
    int*   cursor = srcS + N_EDGES;
    int*   bArr   = (int*)bufB;

    const int mmBlocks   = (N_NODES + 63) / 64;       // 1563
    const int aggBlocks  = (N_NODES + 3) / 4;         // 25000
    const int tailBlocks = (N_NODES + 255) / 256;     // 391

    // CSR build (bucket sort, LDS atomics only)
    k_zero_cur<<<1, 256, 0, stream>>>(cursor);
    k_p1<<<NP1, 1024, 0, stream>>>(ei, cursor, bArr);
    k_p2<<<NBUCK, 1024, 0, stream>>>(bArr, cursor, srcS, off);

    // conv1: y1 = x@W1 ; z1 = y1 + gather-sum(y1)   (gather overwrites bArr)
    k_mm1<<<mmBlocks, 256, 0, stream>>>(x, W1, bufA);
    k_gather_agg<<<aggBlocks, 256, 0, stream>>>(off, srcS, bufA, bufB);
    // conv2: y2 = relu(z1+b1)@W2 ; z2 = y2 + gather-sum(y2)
    k_relu_mm2<<<mmBlocks, 256, 0, stream>>>(bufB, b1, W2, bufA);
    k_gather_agg<<<aggBlocks, 256, 0, stream>>>(off, srcS, bufA, bufB);
    // head
    k_tail<<<tailBlocks, 256, 0, stream>>>(bufB, b2, W3, b3, W4, b4, out);
}

// Round 5
// 301.976 us; speedup vs baseline: 1.2971x; 1.0642x over previous
//
#include <hip/hip_runtime.h>
#include <hip/hip_fp16.h>

#define N_NODES 100000
#define N_EDGES 1600000
#define NBUCK 196            // ceil(N_NODES / 512); bucket = dst >> 9
#define BUCAP 10240          // per-bucket capacity (mean 8192, sigma ~90: +22 sigma)
#define P1_EDGES 8192        // edges per P1 block
#define NP1 196              // ceil(N_EDGES / P1_EDGES)
#define CURPAD 32            // cursor stride (ints): one 128B line per bucket

// ---------------------------------------------------------------------------
// CSR build, atomic-light bucket sort (rebuilt every launch; ws re-poisoned).
// P1: partition edges into 196 coarse buckets (512 nodes each) via LDS
//     histograms; ONE global atomic per (block,bucket), each on its own line.
// P2: per bucket, build node-level CSR entirely in LDS; coalesced output.
// ---------------------------------------------------------------------------
__global__ __launch_bounds__(256) void k_zero_cur(int* __restrict__ cursor) {
    if (threadIdx.x < NBUCK) cursor[threadIdx.x * CURPAD] = 0;
}

__global__ __launch_bounds__(1024) void k_p1(const int* __restrict__ ei,
                                             int* __restrict__ cursor,
                                             int* __restrict__ bArr) {
    __shared__ int hist[NBUCK];
    const int tid = threadIdx.x;
    if (tid < NBUCK) hist[tid] = 0;

    const int eb = blockIdx.x * P1_EDGES;
    int d[8], s[8];
    #pragma unroll
    for (int j = 0; j < 2; ++j) {
        const int e = eb + j * 4096 + tid * 4;
        if (e < N_EDGES) {                       // N_EDGES % 4 == 0: all-or-none
            int4 dd = *(const int4*)&ei[N_EDGES + e];
            int4 ss = *(const int4*)&ei[e];
            d[j*4+0] = dd.x; d[j*4+1] = dd.y; d[j*4+2] = dd.z; d[j*4+3] = dd.w;
            s[j*4+0] = ss.x; s[j*4+1] = ss.y; s[j*4+2] = ss.z; s[j*4+3] = ss.w;
        } else {
            d[j*4+0] = -1; d[j*4+1] = -1; d[j*4+2] = -1; d[j*4+3] = -1;
            s[j*4+0] = 0;  s[j*4+1] = 0;  s[j*4+2] = 0;  s[j*4+3] = 0;
        }
    }
    __syncthreads();
    #pragma unroll
    for (int j = 0; j < 8; ++j)
        if (d[j] >= 0) atomicAdd(&hist[d[j] >> 9], 1);
    __syncthreads();
    if (tid < NBUCK) {
        int c = hist[tid];
        int base = atomicAdd(&cursor[tid * CURPAD], c);  // padded: no line sharing
        hist[tid] = base;                                // reuse hist as write cursor
    }
    __syncthreads();
    #pragma unroll
    for (int j = 0; j < 8; ++j)
        if (d[j] >= 0) {
            int bk  = d[j] >> 9;
            int pos = atomicAdd(&hist[bk], 1);   // LDS rank -> base+rank
            if (pos < BUCAP)
                bArr[bk * BUCAP + pos] = ((d[j] & 511) << 17) | s[j];
        }
}

__global__ __launch_bounds__(1024) void k_p2(const int* __restrict__ bArr,
                                             const int* __restrict__ cursor,
                                             int* __restrict__ srcS,
                                             int* __restrict__ off) {
    __shared__ int hist[512];
    __shared__ int wtot[8];
    __shared__ int curL[NBUCK];
    __shared__ int ordered[BUCAP];
    const int tid = threadIdx.x;
    const int b   = blockIdx.x;
    if (tid < 512)   hist[tid] = 0;
    if (tid < NBUCK) curL[tid] = cursor[tid * CURPAD];
    __syncthreads();

    int n = curL[b]; if (n > BUCAP) n = BUCAP;
    int gBase = 0;
    for (int j = 0; j < NBUCK; ++j) gBase += (j < b) ? curL[j] : 0;   // LDS broadcast

    int pk[10];                                  // static-indexed (rule #20)
    #pragma unroll
    for (int j = 0; j < 10; ++j) {
        int i = tid + j * 1024;
        pk[j] = (i < n) ? bArr[b * BUCAP + i] : -1;
    }
    #pragma unroll
    for (int j = 0; j < 10; ++j)
        if (pk[j] >= 0) atomicAdd(&hist[pk[j] >> 17], 1);
    __syncthreads();

    // exclusive scan of hist[512]: 8 waves shfl-scan + cross-wave fixup
    int v = 0, incl = 0;
    if (tid < 512) {
        v = hist[tid]; incl = v;
        #pragma unroll
        for (int dd = 1; dd < 64; dd <<= 1) {
            int t = __shfl_up(incl, dd, 64);
            if ((tid & 63) >= dd) incl += t;
        }
        if ((tid & 63) == 63) wtot[tid >> 6] = incl;
    }
    __syncthreads();
    if (tid < 512) {
        int add = 0;
        #pragma unroll
        for (int w = 0; w < 8; ++w) add += (w < (tid >> 6)) ? wtot[w] : 0;
        int ex = add + incl - v;
        hist[tid] = ex;                          // becomes rank cursor for phase B
        int node = b * 512 + tid;
        if (node < N_NODES) off[node] = gBase + ex;
    }
    if (b == NBUCK - 1 && tid == 0) off[N_NODES] = N_EDGES;
    __syncthreads();

    #pragma unroll
    for (int j = 0; j < 10; ++j)
        if (pk[j] >= 0) {
            int dl  = pk[j] >> 17;
            int pos = atomicAdd(&hist[dl], 1);
            ordered[pos] = pk[j] & 0x1FFFF;
        }
    __syncthreads();
    for (int i = tid; i < n; i += 1024) srcS[gBase + i] = ordered[i];
}

// ---------------------------------------------------------------------------
// Gather-aggregate (fp16 rows): z[n] = y[n] + sum_{e: dst==n} y[src_e].
// One wave per node; row = 64ch x 2B = 128B = 32 lanes x half2, so the wave
// splits into two halves, each gathering its own edge of a pair: per pair
// per lane = 1 bpermute + 1 dword load (2 rows in flight per instr wave-wide)
// + 2 cvt + 2 adds. fp32 accumulate; fp32 output. Halves both the random
// fetch granule (128B) and the working set (12.8 MB -> better L2 hit).
// ---------------------------------------------------------------------------
__global__ __launch_bounds__(256) void k_gather_agg(const int* __restrict__ off,
                                                    const int* __restrict__ srcS,
                                                    const __half* __restrict__ y16,
                                                    float* __restrict__ z) {
    const int node = blockIdx.x * 4 + (threadIdx.x >> 6);
    if (node >= N_NODES) return;
    const int lane = threadIdx.x & 63;
    const int hf   = lane >> 5;                  // 0: even edges, 1: odd edges
    const int ln32 = lane & 31;
    const int beg = off[node];
    const int end = off[node + 1];

    float2 acc = {0.f, 0.f};
    if (hf == 0) {                               // self term (exact-rounded fp16)
        __half2 hv = *(const __half2*)&y16[((size_t)node << 6) + (ln32 << 1)];
        float2 f = __half22float2(hv);
        acc.x = f.x; acc.y = f.y;
    }

    int i = beg;
    while (i < end) {
        const int rem  = end - i;
        const int take = rem < 64 ? rem : 64;
        int idx = i + lane;
        if (idx > end - 1) idx = end - 1;        // in-range duplicate for lanes >= take
        const int sv = srcS[idx];                // coalesced: 64 edge indices / wave
        int j = 0;
        for (; j + 16 <= take; j += 16) {        // 8 pairs = 16 edges, 8 loads in flight
            const int s0 = __shfl(sv, j + 0  + hf), s1 = __shfl(sv, j + 2  + hf);
            const int s2 = __shfl(sv, j + 4  + hf), s3 = __shfl(sv, j + 6  + hf);
            const int s4 = __shfl(sv, j + 8  + hf), s5 = __shfl(sv, j + 10 + hf);
            const int s6 = __shfl(sv, j + 12 + hf), s7 = __shfl(sv, j + 14 + hf);
            const __half2 h0 = *(const __half2*)&y16[((size_t)s0 << 6) + (ln32 << 1)];
            const __half2 h1 = *(const __half2*)&y16[((size_t)s1 << 6) + (ln32 << 1)];
            const __half2 h2 = *(const __half2*)&y16[((size_t)s2 << 6) + (ln32 << 1)];
            const __half2 h3 = *(const __half2*)&y16[((size_t)s3 << 6) + (ln32 << 1)];
            const __half2 h4 = *(const __half2*)&y16[((size_t)s4 << 6) + (ln32 << 1)];
            const __half2 h5 = *(const __half2*)&y16[((size_t)s5 << 6) + (ln32 << 1)];
            const __half2 h6 = *(const __half2*)&y16[((size_t)s6 << 6) + (ln32 << 1)];
            const __half2 h7 = *(const __half2*)&y16[((size_t)s7 << 6) + (ln32 << 1)];
            float2 f0 = __half22float2(h0), f1 = __half22float2(h1);
            float2 f2 = __half22float2(h2), f3 = __half22float2(h3);
            float2 f4 = __half22float2(h4), f5 = __half22float2(h5);
            float2 f6 = __half22float2(h6), f7 = __half22float2(h7);
            acc.x += ((f0.x + f1.x) + (f2.x + f3.x)) + ((f4.x + f5.x) + (f6.x + f7.x));
            acc.y += ((f0.y + f1.y) + (f2.y + f3.y)) + ((f4.y + f5.y) + (f6.y + f7.y));
        }
        for (; j + 2 <= take; j += 2) {
            const int s = __shfl(sv, j + hf);
            const __half2 hv = *(const __half2*)&y16[((size_t)s << 6) + (ln32 << 1)];
            float2 f = __half22float2(hv);
            acc.x += f.x; acc.y += f.y;
        }
        if (j < take) {                          // odd leftover: full-wave shfl,
            const int s = __shfl(sv, j);         // half-0-predicated accumulate
            if (hf == 0) {
                const __half2 hv = *(const __half2*)&y16[((size_t)s << 6) + (ln32 << 1)];
                float2 f = __half22float2(hv);
                acc.x += f.x; acc.y += f.y;
            }
        }
        i += take;
    }
    // combine the two halves, write fp32 row (32 lanes x 8B, coalesced)
    acc.x += __shfl_xor(acc.x, 32, 64);
    acc.y += __shfl_xor(acc.y, 32, 64);
    if (hf == 0)
        *(float2*)&z[((size_t)node << 6) + (ln32 << 1)] = acc;
}

// ---------------------------------------------------------------------------
// K1: y16 = fp16(x @ W1)  (N x 128 @ 128 x 64).  64x64 block tile, 4x4
// register tile, X staged transposed in LDS. fp16-only output (12.8 MB).
// ---------------------------------------------------------------------------
#define FMA16()                                                       \
    do {                                                              \
        acc0.x += a.x * w.x; acc0.y += a.x * w.y;                     \
        acc0.z += a.x * w.z; acc0.w += a.x * w.w;                     \
        acc1.x += a.y * w.x; acc1.y += a.y * w.y;                     \
        acc1.z += a.y * w.z; acc1.w += a.y * w.w;                     \
        acc2.x += a.z * w.x; acc2.y += a.z * w.y;                     \
        acc2.z += a.z * w.z; acc2.w += a.z * w.w;                     \
        acc3.x += a.w * w.x; acc3.y += a.w * w.y;                     \
        acc3.z += a.w * w.z; acc3.w += a.w * w.w;                     \
    } while (0)

__device__ __forceinline__ void store_h4(__half* p, float4 a) {
    union { __half2 h[2]; uint2 u; } P;
    P.h[0] = __floats2half2_rn(a.x, a.y);
    P.h[1] = __floats2half2_rn(a.z, a.w);
    *(uint2*)p = P.u;
}

__global__ __launch_bounds__(256) void k_mm1(const float* __restrict__ x,
                                             const float* __restrict__ W1,
                                             __half* __restrict__ y16) {
    __shared__ float sW[128 * 64];    // 32 KB, [k][n]
    __shared__ float sxT[128 * 68];   // 34 KB, [k][m] transposed, stride 68
    const int tid  = threadIdx.x;
    const int row0 = blockIdx.x * 64;
    #pragma unroll
    for (int i = tid * 4; i < 128 * 64; i += 1024)
        *(float4*)&sW[i] = *(const float4*)&W1[i];
    #pragma unroll 8
    for (int i = tid; i < 64 * 128; i += 256) {
        int m = i >> 7, k = i & 127;                 // coalesced in k
        int r = row0 + m; if (r >= N_NODES) r = N_NODES - 1;
        sxT[k * 68 + m] = x[(size_t)r * 128 + k];
    }
    __syncthreads();
    const int tx = tid & 15;          // cols tx*4 .. +3
    const int ty = tid >> 4;          // rows ty*4 .. +3
    float4 acc0 = {0.f,0.f,0.f,0.f}, acc1 = {0.f,0.f,0.f,0.f};
    float4 acc2 = {0.f,0.f,0.f,0.f}, acc3 = {0.f,0.f,0.f,0.f};
    #pragma unroll 4
    for (int k = 0; k < 128; ++k) {
        float4 a = *(const float4*)&sxT[k * 68 + ty * 4];
        float4 w = *(const float4*)&sW[k * 64 + tx * 4];
        FMA16();
    }
    const int rb = row0 + ty * 4;
    if (rb + 0 < N_NODES) store_h4(&y16[(size_t)(rb + 0) * 64 + tx * 4], acc0);
    if (rb + 1 < N_NODES) store_h4(&y16[(size_t)(rb + 1) * 64 + tx * 4], acc1);
    if (rb + 2 < N_NODES) store_h4(&y16[(size_t)(rb + 2) * 64 + tx * 4], acc2);
    if (rb + 3 < N_NODES) store_h4(&y16[(size_t)(rb + 3) * 64 + tx * 4], acc3);
}

// ---------------------------------------------------------------------------
// K3: h1 = relu(z1 + b1);  y16 = fp16(h1 @ W2)  (64x64).
// ---------------------------------------------------------------------------
__global__ __launch_bounds__(256) void k_relu_mm2(const float* __restrict__ z1,
                                                  const float* __restrict__ b1,
                                                  const float* __restrict__ W2,
                                                  __half* __restrict__ y16) {
    __shared__ float sW[64 * 64];     // 16 KB, [k][n]
    __shared__ float shT[64 * 68];    // 17 KB, [k][m] transposed
    const int tid  = threadIdx.x;
    const int row0 = blockIdx.x * 64;
    #pragma unroll
    for (int i = tid * 4; i < 64 * 64; i += 1024)
        *(float4*)&sW[i] = *(const float4*)&W2[i];
    #pragma unroll 8
    for (int i = tid; i < 64 * 64; i += 256) {
        int m = i >> 6, k = i & 63;                  // coalesced in k
        int r = row0 + m; if (r >= N_NODES) r = N_NODES - 1;
        shT[k * 68 + m] = fmaxf(z1[(size_t)r * 64 + k] + b1[k], 0.f);
    }
    __syncthreads();
    const int tx = tid & 15;
    const int ty = tid >> 4;
    float4 acc0 = {0.f,0.f,0.f,0.f}, acc1 = {0.f,0.f,0.f,0.f};
    float4 acc2 = {0.f,0.f,0.f,0.f}, acc3 = {0.f,0.f,0.f,0.f};
    #pragma unroll 4
    for (int k = 0; k < 64; ++k) {
        float4 a = *(const float4*)&shT[k * 68 + ty * 4];
        float4 w = *(const float4*)&sW[k * 64 + tx * 4];
        FMA16();
    }
    const int rb = row0 + ty * 4;
    if (rb + 0 < N_NODES) store_h4(&y16[(size_t)(rb + 0) * 64 + tx * 4], acc0);
    if (rb + 1 < N_NODES) store_h4(&y16[(size_t)(rb + 1) * 64 + tx * 4], acc1);
    if (rb + 2 < N_NODES) store_h4(&y16[(size_t)(rb + 2) * 64 + tx * 4], acc2);
    if (rb + 3 < N_NODES) store_h4(&y16[(size_t)(rb + 3) * 64 + tx * 4], acc3);
}

// ---------------------------------------------------------------------------
// K5: per-node tail: h2 = relu(z2+b2); h3 = relu(h2@W3+b3); out = h3@W4+b4.
// ---------------------------------------------------------------------------
__global__ __launch_bounds__(256) void k_tail(const float* __restrict__ z2,
                                              const float* __restrict__ b2,
                                              const float* __restrict__ W3,
                                              const float* __restrict__ b3,
                                              const float* __restrict__ W4,
                                              const float* __restrict__ b4,
                                              float* __restrict__ out) {
    __shared__ float sW3[64 * 16];
    __shared__ float sW4[16];
    __shared__ float sb3[16];
    const int tid = threadIdx.x;
    *(float4*)&sW3[tid * 4] = *(const float4*)&W3[tid * 4];
    if (tid < 16) { sW4[tid] = W4[tid]; sb3[tid] = b3[tid]; }
    __syncthreads();
    const int node = blockIdx.x * 256 + tid;
    if (node >= N_NODES) return;

    float h[64];
    const float4* zp = (const float4*)&z2[(size_t)node * 64];
    #pragma unroll
    for (int i = 0; i < 16; ++i) {
        float4 v  = zp[i];
        float4 bb = *(const float4*)&b2[i * 4];
        h[i * 4 + 0] = fmaxf(v.x + bb.x, 0.f);
        h[i * 4 + 1] = fmaxf(v.y + bb.y, 0.f);
        h[i * 4 + 2] = fmaxf(v.z + bb.z, 0.f);
        h[i * 4 + 3] = fmaxf(v.w + bb.w, 0.f);
    }
    float acc[16];
    #pragma unroll
    for (int j = 0; j < 16; ++j) acc[j] = sb3[j];
    #pragma unroll 8
    for (int k = 0; k < 64; ++k) {
        float hv = h[k];
        #pragma unroll
        for (int j = 0; j < 16; ++j) acc[j] += hv * sW3[k * 16 + j];
    }
    float o = b4[0];
    #pragma unroll
    for (int j = 0; j < 16; ++j) o += fmaxf(acc[j], 0.f) * sW4[j];
    out[node] = o;
}

extern "C" void kernel_launch(void* const* d_in, const int* in_sizes, int n_in,
                              void* d_out, int out_size, void* d_ws, size_t ws_size,
                              hipStream_t stream) {
    const float* x  = (const float*)d_in[0];
    const int*   ei = (const int*)d_in[1];
    const float* W1 = (const float*)d_in[2];
    const float* b1 = (const float*)d_in[3];
    const float* W2 = (const float*)d_in[4];
    const float* b2 = (const float*)d_in[5];
    const float* W3 = (const float*)d_in[6];
    const float* b3 = (const float*)d_in[7];
    const float* W4 = (const float*)d_in[8];
    const float* b4 = (const float*)d_in[9];
    float* out = (float*)d_out;

    // ws layout: bufZ (fp32, 25.6MB) | y16 (fp16, 12.8MB) | off | srcS | cursor
    // bufZ lifecycle: bArr (p1/p2) -> z1 (gather1, read by mm2) -> z2
    // (gather2 overwrites, mm2 already done) -> tail input.
    float*  bufZ   = (float*)d_ws;
    __half* y16    = (__half*)(bufZ + (size_t)N_NODES * 64);
    int*    off    = (int*)(y16 + (size_t)N_NODES * 64);
    int*    srcS   = off + N_NODES + 4;       // 16B alignment slack
    int*    cursor = srcS + N_EDGES;
    int*    bArr   = (int*)bufZ;

    const int mmBlocks   = (N_NODES + 63) / 64;       // 1563
    const int aggBlocks  = (N_NODES + 3) / 4;         // 25000
    const int tailBlocks = (N_NODES + 255) / 256;     // 391

    // CSR build (bucket sort, LDS atomics only)
    k_zero_cur<<<1, 256, 0, stream>>>(cursor);
    k_p1<<<NP1, 1024, 0, stream>>>(ei, cursor, bArr);
    k_p2<<<NBUCK, 1024, 0, stream>>>(bArr, cursor, srcS, off);

    // conv1: y16 = fp16(x@W1) ; z1 = agg(y16)   (z1 overwrites bArr: p2 done)
    k_mm1<<<mmBlocks, 256, 0, stream>>>(x, W1, y16);
    k_gather_agg<<<aggBlocks, 256, 0, stream>>>(off, srcS, y16, bufZ);
    // conv2: y16 = fp16(relu(z1+b1)@W2) ; z2 = agg(y16)  (z2 overwrites z1)
    k_relu_mm2<<<mmBlocks, 256, 0, stream>>>(bufZ, b1, W2, y16);
    k_gather_agg<<<aggBlocks, 256, 0, stream>>>(off, srcS, y16, bufZ);
    // head
    k_tail<<<tailBlocks, 256, 0, stream>>>(bufZ, b2, W3, b3, W4, b4, out);
}

// Round 6
// 284.176 us; speedup vs baseline: 1.3783x; 1.0626x over previous
//
#include <hip/hip_runtime.h>
#include <hip/hip_fp16.h>

#define N_NODES 100000
#define N_EDGES 1600000
#define NBUCK 196            // ceil(N_NODES / 512); bucket = dst >> 9
#define BUCAP 10240          // per-bucket capacity (mean 8192, sigma ~90: +22 sigma)
#define P1_EDGES 8192        // edges per P1 block
#define NP1 196              // ceil(N_EDGES / P1_EDGES)
#define CURPAD 32            // cursor stride (ints): one 128B line per bucket

// ---------------------------------------------------------------------------
// CSR build, atomic-light bucket sort (rebuilt every launch; ws re-poisoned).
// ---------------------------------------------------------------------------
__global__ __launch_bounds__(256) void k_zero_cur(int* __restrict__ cursor) {
    if (threadIdx.x < NBUCK) cursor[threadIdx.x * CURPAD] = 0;
}

__global__ __launch_bounds__(1024) void k_p1(const int* __restrict__ ei,
                                             int* __restrict__ cursor,
                                             int* __restrict__ bArr) {
    __shared__ int hist[NBUCK];
    const int tid = threadIdx.x;
    if (tid < NBUCK) hist[tid] = 0;

    const int eb = blockIdx.x * P1_EDGES;
    int d[8], s[8];
    #pragma unroll
    for (int j = 0; j < 2; ++j) {
        const int e = eb + j * 4096 + tid * 4;
        if (e < N_EDGES) {                       // N_EDGES % 4 == 0: all-or-none
            int4 dd = *(const int4*)&ei[N_EDGES + e];
            int4 ss = *(const int4*)&ei[e];
            d[j*4+0] = dd.x; d[j*4+1] = dd.y; d[j*4+2] = dd.z; d[j*4+3] = dd.w;
            s[j*4+0] = ss.x; s[j*4+1] = ss.y; s[j*4+2] = ss.z; s[j*4+3] = ss.w;
        } else {
            d[j*4+0] = -1; d[j*4+1] = -1; d[j*4+2] = -1; d[j*4+3] = -1;
            s[j*4+0] = 0;  s[j*4+1] = 0;  s[j*4+2] = 0;  s[j*4+3] = 0;
        }
    }
    __syncthreads();
    #pragma unroll
    for (int j = 0; j < 8; ++j)
        if (d[j] >= 0) atomicAdd(&hist[d[j] >> 9], 1);
    __syncthreads();
    if (tid < NBUCK) {
        int c = hist[tid];
        int base = atomicAdd(&cursor[tid * CURPAD], c);  // padded: no line sharing
        hist[tid] = base;                                // reuse hist as write cursor
    }
    __syncthreads();
    #pragma unroll
    for (int j = 0; j < 8; ++j)
        if (d[j] >= 0) {
            int bk  = d[j] >> 9;
            int pos = atomicAdd(&hist[bk], 1);   // LDS rank -> base+rank
            if (pos < BUCAP)
                bArr[bk * BUCAP + pos] = ((d[j] & 511) << 17) | s[j];
        }
}

__global__ __launch_bounds__(1024) void k_p2(const int* __restrict__ bArr,
                                             const int* __restrict__ cursor,
                                             int* __restrict__ srcS,
                                             int* __restrict__ off) {
    __shared__ int hist[512];
    __shared__ int wtot[8];
    __shared__ int curL[NBUCK];
    __shared__ int ordered[BUCAP];
    const int tid = threadIdx.x;
    const int b   = blockIdx.x;
    if (tid < 512)   hist[tid] = 0;
    if (tid < NBUCK) curL[tid] = cursor[tid * CURPAD];
    __syncthreads();

    int n = curL[b]; if (n > BUCAP) n = BUCAP;
    int gBase = 0;
    for (int j = 0; j < NBUCK; ++j) gBase += (j < b) ? curL[j] : 0;   // LDS broadcast

    int pk[10];                                  // static-indexed (rule #20)
    #pragma unroll
    for (int j = 0; j < 10; ++j) {
        int i = tid + j * 1024;
        pk[j] = (i < n) ? bArr[b * BUCAP + i] : -1;
    }
    #pragma unroll
    for (int j = 0; j < 10; ++j)
        if (pk[j] >= 0) atomicAdd(&hist[pk[j] >> 17], 1);
    __syncthreads();

    // exclusive scan of hist[512]: 8 waves shfl-scan + cross-wave fixup
    int v = 0, incl = 0;
    if (tid < 512) {
        v = hist[tid]; incl = v;
        #pragma unroll
        for (int dd = 1; dd < 64; dd <<= 1) {
            int t = __shfl_up(incl, dd, 64);
            if ((tid & 63) >= dd) incl += t;
        }
        if ((tid & 63) == 63) wtot[tid >> 6] = incl;
    }
    __syncthreads();
    if (tid < 512) {
        int add = 0;
        #pragma unroll
        for (int w = 0; w < 8; ++w) add += (w < (tid >> 6)) ? wtot[w] : 0;
        int ex = add + incl - v;
        hist[tid] = ex;                          // becomes rank cursor for phase B
        int node = b * 512 + tid;
        if (node < N_NODES) off[node] = gBase + ex;
    }
    if (b == NBUCK - 1 && tid == 0) off[N_NODES] = N_EDGES;
    __syncthreads();

    #pragma unroll
    for (int j = 0; j < 10; ++j)
        if (pk[j] >= 0) {
            int dl  = pk[j] >> 17;
            int pos = atomicAdd(&hist[dl], 1);
            ordered[pos] = pk[j] & 0x1FFFF;
        }
    __syncthreads();
    for (int i = tid; i < n; i += 1024) srcS[gBase + i] = ordered[i];
}

// ---------------------------------------------------------------------------
// Common gather core (fp16 rows): acc = y[n] + sum_{e: dst==n} y[src_e].
// One wave per node; wave splits into two halves, each gathering its own edge
// of a pair. Returns per-lane float2 BEFORE the half-combine.
// ---------------------------------------------------------------------------
__device__ __forceinline__ float2 gather_core(const int* __restrict__ off,
                                              const int* __restrict__ srcS,
                                              const __half* __restrict__ y16,
                                              int node, int lane) {
    const int hf   = lane >> 5;
    const int ln32 = lane & 31;
    const int beg = off[node];
    const int end = off[node + 1];

    float2 acc = {0.f, 0.f};
    if (hf == 0) {                               // self term
        __half2 hv = *(const __half2*)&y16[((size_t)node << 6) + (ln32 << 1)];
        float2 f = __half22float2(hv);
        acc.x = f.x; acc.y = f.y;
    }

    int i = beg;
    while (i < end) {
        const int rem  = end - i;
        const int take = rem < 64 ? rem : 64;
        int idx = i + lane;
        if (idx > end - 1) idx = end - 1;        // in-range duplicate for lanes >= take
        const int sv = srcS[idx];                // coalesced: 64 edge indices / wave
        int j = 0;
        for (; j + 16 <= take; j += 16) {        // 8 pairs = 16 edges, 8 loads in flight
            const int s0 = __shfl(sv, j + 0  + hf), s1 = __shfl(sv, j + 2  + hf);
            const int s2 = __shfl(sv, j + 4  + hf), s3 = __shfl(sv, j + 6  + hf);
            const int s4 = __shfl(sv, j + 8  + hf), s5 = __shfl(sv, j + 10 + hf);
            const int s6 = __shfl(sv, j + 12 + hf), s7 = __shfl(sv, j + 14 + hf);
            const __half2 h0 = *(const __half2*)&y16[((size_t)s0 << 6) + (ln32 << 1)];
            const __half2 h1 = *(const __half2*)&y16[((size_t)s1 << 6) + (ln32 << 1)];
            const __half2 h2 = *(const __half2*)&y16[((size_t)s2 << 6) + (ln32 << 1)];
            const __half2 h3 = *(const __half2*)&y16[((size_t)s3 << 6) + (ln32 << 1)];
            const __half2 h4 = *(const __half2*)&y16[((size_t)s4 << 6) + (ln32 << 1)];
            const __half2 h5 = *(const __half2*)&y16[((size_t)s5 << 6) + (ln32 << 1)];
            const __half2 h6 = *(const __half2*)&y16[((size_t)s6 << 6) + (ln32 << 1)];
            const __half2 h7 = *(const __half2*)&y16[((size_t)s7 << 6) + (ln32 << 1)];
            float2 f0 = __half22float2(h0), f1 = __half22float2(h1);
            float2 f2 = __half22float2(h2), f3 = __half22float2(h3);
            float2 f4 = __half22float2(h4), f5 = __half22float2(h5);
            float2 f6 = __half22float2(h6), f7 = __half22float2(h7);
            acc.x += ((f0.x + f1.x) + (f2.x + f3.x)) + ((f4.x + f5.x) + (f6.x + f7.x));
            acc.y += ((f0.y + f1.y) + (f2.y + f3.y)) + ((f4.y + f5.y) + (f6.y + f7.y));
        }
        for (; j + 2 <= take; j += 2) {
            const int s = __shfl(sv, j + hf);
            const __half2 hv = *(const __half2*)&y16[((size_t)s << 6) + (ln32 << 1)];
            float2 f = __half22float2(hv);
            acc.x += f.x; acc.y += f.y;
        }
        if (j < take) {                          // odd leftover: hf==0 half handles it
            const int s = __shfl(sv, j);
            if (hf == 0) {
                const __half2 hv = *(const __half2*)&y16[((size_t)s << 6) + (ln32 << 1)];
                float2 f = __half22float2(hv);
                acc.x += f.x; acc.y += f.y;
            }
        }
        i += take;
    }
    return acc;
}

// ---------------------------------------------------------------------------
// Gather1 fused epilogue: h1 = relu(agg(y1) + b1) stored as fp16 (12.8 MB).
// ---------------------------------------------------------------------------
__global__ __launch_bounds__(256) void k_gather_h1(const int* __restrict__ off,
                                                   const int* __restrict__ srcS,
                                                   const __half* __restrict__ y16,
                                                   const float* __restrict__ b1,
                                                   __half* __restrict__ h16) {
    const int node = blockIdx.x * 4 + (threadIdx.x >> 6);
    if (node >= N_NODES) return;
    const int lane = threadIdx.x & 63;
    const int hf = lane >> 5, ln32 = lane & 31;
    float2 bb = {0.f, 0.f};
    if (hf == 0) bb = *(const float2*)&b1[ln32 * 2];

    float2 acc = gather_core(off, srcS, y16, node, lane);
    acc.x += __shfl_xor(acc.x, 32, 64);
    acc.y += __shfl_xor(acc.y, 32, 64);
    if (hf == 0) {
        float hx = fmaxf(acc.x + bb.x, 0.f);
        float hy = fmaxf(acc.y + bb.y, 0.f);
        *(__half2*)&h16[((size_t)node << 6) + (ln32 << 1)] = __floats2half2_rn(hx, hy);
    }
}

// ---------------------------------------------------------------------------
// Gather2 fused with the whole MLP head (z2 never materializes):
// z2 = agg(y2); h2 = relu(z2+b2); h3 = relu(h2@W3+b3); out = h3@W4+b4.
// Head is computed in-wave: row exchanged via 1KB intra-wave LDS, 4 lanes per
// W3-column (W3 column-slices preloaded in registers), shfl_xor reductions.
// All-fp32 math, identical to the old k_tail.
// ---------------------------------------------------------------------------
__global__ __launch_bounds__(256) void k_gather_tail(const int* __restrict__ off,
                                                     const int* __restrict__ srcS,
                                                     const __half* __restrict__ y16,
                                                     const float* __restrict__ b2,
                                                     const float* __restrict__ W3,
                                                     const float* __restrict__ b3,
                                                     const float* __restrict__ W4,
                                                     const float* __restrict__ b4,
                                                     float* __restrict__ out) {
    __shared__ float sh2[4][64];
    const int wv   = threadIdx.x >> 6;
    const int node = blockIdx.x * 4 + wv;
    if (node >= N_NODES) return;
    const int lane = threadIdx.x & 63;
    const int hf = lane >> 5, ln32 = lane & 31;

    // per-lane head constants (one-time loads; W3/W4/b3 are L2-hot, 4KB)
    const int jj = lane & 15, pp = lane >> 4;    // 4 lanes cooperate per output jj
    float w3r[16];
    #pragma unroll
    for (int k = 0; k < 16; ++k) w3r[k] = W3[(pp * 16 + k) * 16 + jj];
    const float b3j = b3[jj], w4j = W4[jj], b4v = b4[0];
    float2 bb = {0.f, 0.f};
    if (hf == 0) bb = *(const float2*)&b2[ln32 * 2];

    float2 acc = gather_core(off, srcS, y16, node, lane);
    acc.x += __shfl_xor(acc.x, 32, 64);
    acc.y += __shfl_xor(acc.y, 32, 64);
    if (hf == 0) {
        float hx = fmaxf(acc.x + bb.x, 0.f);
        float hy = fmaxf(acc.y + bb.y, 0.f);
        *(float2*)&sh2[wv][ln32 * 2] = make_float2(hx, hy);
    }
    // intra-wave LDS exchange: per-wave DS ordering guarantees the write is
    // visible to this wave's reads (no cross-wave consumers -> no barrier).
    const float4 hA = *(const float4*)&sh2[wv][pp * 16 + 0];
    const float4 hB = *(const float4*)&sh2[wv][pp * 16 + 4];
    const float4 hC = *(const float4*)&sh2[wv][pp * 16 + 8];
    const float4 hD = *(const float4*)&sh2[wv][pp * 16 + 12];
    float part = hA.x * w3r[0]  + hA.y * w3r[1]  + hA.z * w3r[2]  + hA.w * w3r[3]
               + hB.x * w3r[4]  + hB.y * w3r[5]  + hB.z * w3r[6]  + hB.w * w3r[7]
               + hC.x * w3r[8]  + hC.y * w3r[9]  + hC.z * w3r[10] + hC.w * w3r[11]
               + hD.x * w3r[12] + hD.y * w3r[13] + hD.z * w3r[14] + hD.w * w3r[15];
    part += __shfl_xor(part, 16, 64);            // reduce over pp (bits 4,5)
    part += __shfl_xor(part, 32, 64);
    float o = fmaxf(part + b3j, 0.f) * w4j;
    o += __shfl_xor(o, 1, 64);                   // reduce over jj (bits 0..3)
    o += __shfl_xor(o, 2, 64);
    o += __shfl_xor(o, 4, 64);
    o += __shfl_xor(o, 8, 64);
    if (lane == 0) out[node] = o + b4v;
}

// ---------------------------------------------------------------------------
// K1: y16 = fp16(x @ W1)  (N x 128 @ 128 x 64).  64x64 block tile, 4x4
// register tile, X staged transposed in LDS.
// ---------------------------------------------------------------------------
#define FMA16()                                                       \
    do {                                                              \
        acc0.x += a.x * w.x; acc0.y += a.x * w.y;                     \
        acc0.z += a.x * w.z; acc0.w += a.x * w.w;                     \
        acc1.x += a.y * w.x; acc1.y += a.y * w.y;                     \
        acc1.z += a.y * w.z; acc1.w += a.y * w.w;                     \
        acc2.x += a.z * w.x; acc2.y += a.z * w.y;                     \
        acc2.z += a.z * w.z; acc2.w += a.z * w.w;                     \
        acc3.x += a.w * w.x; acc3.y += a.w * w.y;                     \
        acc3.z += a.w * w.z; acc3.w += a.w * w.w;                     \
    } while (0)

__device__ __forceinline__ void store_h4(__half* p, float4 a) {
    union { __half2 h[2]; uint2 u; } P;
    P.h[0] = __floats2half2_rn(a.x, a.y);
    P.h[1] = __floats2half2_rn(a.z, a.w);
    *(uint2*)p = P.u;
}

__global__ __launch_bounds__(256) void k_mm1(const float* __restrict__ x,
                                             const float* __restrict__ W1,
                                             __half* __restrict__ y16) {
    __shared__ float sW[128 * 64];    // 32 KB, [k][n]
    __shared__ float sxT[128 * 68];   // 34 KB, [k][m] transposed, stride 68
    const int tid  = threadIdx.x;
    const int row0 = blockIdx.x * 64;
    #pragma unroll
    for (int i = tid * 4; i < 128 * 64; i += 1024)
        *(float4*)&sW[i] = *(const float4*)&W1[i];
    #pragma unroll 8
    for (int i = tid; i < 64 * 128; i += 256) {
        int m = i >> 7, k = i & 127;                 // coalesced in k
        int r = row0 + m; if (r >= N_NODES) r = N_NODES - 1;
        sxT[k * 68 + m] = x[(size_t)r * 128 + k];
    }
    __syncthreads();
    const int tx = tid & 15;          // cols tx*4 .. +3
    const int ty = tid >> 4;          // rows ty*4 .. +3
    float4 acc0 = {0.f,0.f,0.f,0.f}, acc1 = {0.f,0.f,0.f,0.f};
    float4 acc2 = {0.f,0.f,0.f,0.f}, acc3 = {0.f,0.f,0.f,0.f};
    #pragma unroll 4
    for (int k = 0; k < 128; ++k) {
        float4 a = *(const float4*)&sxT[k * 68 + ty * 4];
        float4 w = *(const float4*)&sW[k * 64 + tx * 4];
        FMA16();
    }
    const int rb = row0 + ty * 4;
    if (rb + 0 < N_NODES) store_h4(&y16[(size_t)(rb + 0) * 64 + tx * 4], acc0);
    if (rb + 1 < N_NODES) store_h4(&y16[(size_t)(rb + 1) * 64 + tx * 4], acc1);
    if (rb + 2 < N_NODES) store_h4(&y16[(size_t)(rb + 2) * 64 + tx * 4], acc2);
    if (rb + 3 < N_NODES) store_h4(&y16[(size_t)(rb + 3) * 64 + tx * 4], acc3);
}

// ---------------------------------------------------------------------------
// K3: y16 = fp16(h1 @ W2)  (64x64).  h1 comes in fp16 (relu/bias already
// applied by k_gather_h1).
// ---------------------------------------------------------------------------
__global__ __launch_bounds__(256) void k_mm2(const __half* __restrict__ h16,
                                             const float* __restrict__ W2,
                                             __half* __restrict__ y16) {
    __shared__ float sW[64 * 64];     // 16 KB, [k][n]
    __shared__ float shT[64 * 68];    // 17 KB, [k][m] transposed
    const int tid  = threadIdx.x;
    const int row0 = blockIdx.x * 64;
    #pragma unroll
    for (int i = tid * 4; i < 64 * 64; i += 1024)
        *(float4*)&sW[i] = *(const float4*)&W2[i];
    #pragma unroll
    for (int i = tid * 2; i < 64 * 64; i += 512) {
        int m = i >> 6, k = i & 63;                  // coalesced in k (half2)
        int r = row0 + m; if (r >= N_NODES) r = N_NODES - 1;
        __half2 hv = *(const __half2*)&h16[(size_t)r * 64 + k];
        float2 f = __half22float2(hv);
        shT[k * 68 + m]       = f.x;
        shT[(k + 1) * 68 + m] = f.y;
    }
    __syncthreads();
    const int tx = tid & 15;
    const int ty = tid >> 4;
    float4 acc0 = {0.f,0.f,0.f,0.f}, acc1 = {0.f,0.f,0.f,0.f};
    float4 acc2 = {0.f,0.f,0.f,0.f}, acc3 = {0.f,0.f,0.f,0.f};
    #pragma unroll 4
    for (int k = 0; k < 64; ++k) {
        float4 a = *(const float4*)&shT[k * 68 + ty * 4];
        float4 w = *(const float4*)&sW[k * 64 + tx * 4];
        FMA16();
    }
    const int rb = row0 + ty * 4;
    if (rb + 0 < N_NODES) store_h4(&y16[(size_t)(rb + 0) * 64 + tx * 4], acc0);
    if (rb + 1 < N_NODES) store_h4(&y16[(size_t)(rb + 1) * 64 + tx * 4], acc1);
    if (rb + 2 < N_NODES) store_h4(&y16[(size_t)(rb + 2) * 64 + tx * 4], acc2);
    if (rb + 3 < N_NODES) store_h4(&y16[(size_t)(rb + 3) * 64 + tx * 4], acc3);
}

extern "C" void kernel_launch(void* const* d_in, const int* in_sizes, int n_in,
                              void* d_out, int out_size, void* d_ws, size_t ws_size,
                              hipStream_t stream) {
    const float* x  = (const float*)d_in[0];
    const int*   ei = (const int*)d_in[1];
    const float* W1 = (const float*)d_in[2];
    const float* b1 = (const float*)d_in[3];
    const float* W2 = (const float*)d_in[4];
    const float* b2 = (const float*)d_in[5];
    const float* W3 = (const float*)d_in[6];
    const float* b3 = (const float*)d_in[7];
    const float* W4 = (const float*)d_in[8];
    const float* b4 = (const float*)d_in[9];
    float* out = (float*)d_out;

    // ws layout: h16 (12.8MB, aliases bArr 8MB) | y16 (12.8MB) | off | srcS | cursor
    // Order: p1/p2 use bArr -> mm1 writes y16 -> gather_h1 reads y16, writes
    // h16 (p2 done) -> mm2 reads h16, writes y16 (y1 dead) -> gather_tail.
    __half* h16    = (__half*)d_ws;
    __half* y16    = h16 + (size_t)N_NODES * 64;
    int*    off    = (int*)(y16 + (size_t)N_NODES * 64);
    int*    srcS   = off + N_NODES + 4;       // 16B alignment slack
    int*    cursor = srcS + N_EDGES;
    int*    bArr   = (int*)d_ws;

    const int mmBlocks  = (N_NODES + 63) / 64;        // 1563
    const int aggBlocks = (N_NODES + 3) / 4;          // 25000

    // CSR build (bucket sort, LDS atomics only)
    k_zero_cur<<<1, 256, 0, stream>>>(cursor);
    k_p1<<<NP1, 1024, 0, stream>>>(ei, cursor, bArr);
    k_p2<<<NBUCK, 1024, 0, stream>>>(bArr, cursor, srcS, off);

    // conv1: y16 = fp16(x@W1); h16 = fp16(relu(agg(y16)+b1))
    k_mm1<<<mmBlocks, 256, 0, stream>>>(x, W1, y16);
    k_gather_h1<<<aggBlocks, 256, 0, stream>>>(off, srcS, y16, b1, h16);
    // conv2 + head: y16 = fp16(h16@W2); out = head(agg(y16))
    k_mm2<<<mmBlocks, 256, 0, stream>>>(h16, W2, y16);
    k_gather_tail<<<aggBlocks, 256, 0, stream>>>(off, srcS, y16, b2, W3, b3, W4, b4, out);
}